// Round 7
// baseline (183.132 us; speedup 1.0000x reference)
//
#include <hip/hip_runtime.h>
#include <hip/hip_cooperative_groups.h>

namespace cg = cooperative_groups;

// Problem constants (match the JAX reference).
constexpr int NSEG = 10000;
constexpr int BB   = 4;
constexpr int SS   = 200000;    // divisible by 4
constexpr int DD   = 64;        // 16 float4 per row

constexpr int CAP     = 48;     // bucket capacity per segment (mean 20, P(>48) ~ 1e-8)
constexpr int OVF_CAP = 4096;   // overflow list capacity (empty in practice)
constexpr int NTHR    = 256;

// ---------------------------------------------------------------------------
// Shared device code
__device__ __forceinline__ void bucket_body(int gtid, int gsz,
                                            const int4* __restrict__ seg4,
                                            int* __restrict__ cnt,
                                            int* __restrict__ ovf_cnt,
                                            int* __restrict__ bucket,
                                            int* __restrict__ ovf) {
    for (int i = gtid; i < SS / 4; i += gsz) {
        int4 sg = seg4[i];
        int base = i * 4;
        int ss[4] = {sg.x, sg.y, sg.z, sg.w};
        #pragma unroll
        for (int k = 0; k < 4; ++k) {
            int s = ss[k];
            int p = atomicAdd(&cnt[s], 1);
            if (p < CAP) {
                bucket[s * CAP + p] = base + k;
            } else {
                int o = atomicAdd(ovf_cnt, 1);
                if (o < OVF_CAP) ovf[o] = base + k;
            }
        }
    }
}

// Gather-sum for one segment. Wave-per-segment; lane = (d4, b).
__device__ __forceinline__ void gather_segment(int s, int d4, int b,
                                               const float4* __restrict__ v4,
                                               const int* __restrict__ cnt,
                                               const int* __restrict__ bucket,
                                               const int* __restrict__ seg,
                                               const int* __restrict__ ovf_cnt,
                                               const int* __restrict__ ovf,
                                               float4* __restrict__ out4) {
    int n = cnt[s];
    if (n > CAP) n = CAP;
    const int* bk = bucket + s * CAP;                 // 192B-aligned
    const float4* vb = v4 + (size_t)b * SS * 16;

    float4 acc = make_float4(0.f, 0.f, 0.f, 0.f);

    int j = 0;
    for (; j + 7 < n; j += 8) {                       // 8 rows in flight per lane
        int4 r0 = *(const int4*)(bk + j);
        int4 r1 = *(const int4*)(bk + j + 4);
        float4 a0 = vb[(size_t)r0.x * 16 + d4];
        float4 a1 = vb[(size_t)r0.y * 16 + d4];
        float4 a2 = vb[(size_t)r0.z * 16 + d4];
        float4 a3 = vb[(size_t)r0.w * 16 + d4];
        float4 a4 = vb[(size_t)r1.x * 16 + d4];
        float4 a5 = vb[(size_t)r1.y * 16 + d4];
        float4 a6 = vb[(size_t)r1.z * 16 + d4];
        float4 a7 = vb[(size_t)r1.w * 16 + d4];
        acc.x += ((a0.x + a1.x) + (a2.x + a3.x)) + ((a4.x + a5.x) + (a6.x + a7.x));
        acc.y += ((a0.y + a1.y) + (a2.y + a3.y)) + ((a4.y + a5.y) + (a6.y + a7.y));
        acc.z += ((a0.z + a1.z) + (a2.z + a3.z)) + ((a4.z + a5.z) + (a6.z + a7.z));
        acc.w += ((a0.w + a1.w) + (a2.w + a3.w)) + ((a4.w + a5.w) + (a6.w + a7.w));
    }
    for (; j + 3 < n; j += 4) {
        int4 r0 = *(const int4*)(bk + j);
        float4 a0 = vb[(size_t)r0.x * 16 + d4];
        float4 a1 = vb[(size_t)r0.y * 16 + d4];
        float4 a2 = vb[(size_t)r0.z * 16 + d4];
        float4 a3 = vb[(size_t)r0.w * 16 + d4];
        acc.x += (a0.x + a1.x) + (a2.x + a3.x);
        acc.y += (a0.y + a1.y) + (a2.y + a3.y);
        acc.z += (a0.z + a1.z) + (a2.z + a3.z);
        acc.w += (a0.w + a1.w) + (a2.w + a3.w);
    }
    for (; j < n; ++j) {
        int r0 = bk[j];
        float4 a0 = vb[(size_t)r0 * 16 + d4];
        acc.x += a0.x; acc.y += a0.y; acc.z += a0.z; acc.w += a0.w;
    }

    // Overflow fixup (rows beyond CAP) — empty in practice, one cached load.
    int no = *ovf_cnt;
    if (no > 0) {
        if (no > OVF_CAP) no = OVF_CAP;
        for (int t = 0; t < no; ++t) {
            int r = ovf[t];
            if (seg[r] == s) {
                float4 a0 = vb[(size_t)r * 16 + d4];
                acc.x += a0.x; acc.y += a0.y; acc.z += a0.z; acc.w += a0.w;
            }
        }
    }

    out4[((size_t)b * NSEG + s) * 16 + d4] = acc;     // written exactly once
}

// ---------------------------------------------------------------------------
// Fused cooperative kernel: zero -> bucket -> gather. 0 LDS, low VGPR.
__global__ void __launch_bounds__(NTHR)
fused_kernel(const float4* __restrict__ v4,
             const int*    __restrict__ seg,
             int*          __restrict__ cnt,
             int*          __restrict__ ovf_cnt,
             int*          __restrict__ bucket,
             int*          __restrict__ ovf,
             float4*       __restrict__ out4) {
    cg::grid_group grid = cg::this_grid();
    const int gtid = blockIdx.x * NTHR + threadIdx.x;
    const int gsz  = gridDim.x * NTHR;

    // Phase 0: zero cnt + ovf_cnt
    for (int i = gtid; i <= NSEG; i += gsz) {
        if (i < NSEG) cnt[i] = 0;
        else          *ovf_cnt = 0;
    }
    grid.sync();

    // Phase 1: histogram + bucket scatter
    bucket_body(gtid, gsz, (const int4*)seg, cnt, ovf_cnt, bucket, ovf);
    grid.sync();

    // Phase 2: gather, wave per segment (grid-stride over segments)
    const int lane = threadIdx.x & 63;
    const int d4   = lane & 15;
    const int b    = lane >> 4;
    const int wid  = gtid >> 6;
    const int nw   = gsz >> 6;
    for (int s = wid; s < NSEG; s += nw)
        gather_segment(s, d4, b, v4, cnt, bucket, seg, ovf_cnt, ovf, out4);
}

// ---------------------------------------------------------------------------
// Fallback path (round-6, proven): 3 dispatches.
__global__ void bucket_kernel(const int4* __restrict__ seg4,
                              int* __restrict__ cnt,
                              int* __restrict__ ovf_cnt,
                              int* __restrict__ bucket,
                              int* __restrict__ ovf) {
    int i = blockIdx.x * blockDim.x + threadIdx.x;
    if (i >= SS / 4) return;
    bucket_body(i, SS / 4 + (1 << 30), seg4, cnt, ovf_cnt, bucket, ovf);  // single trip
}

__global__ void __launch_bounds__(NTHR)
gather_kernel(const float4* __restrict__ v4,
              const int* __restrict__ cnt,
              const int* __restrict__ bucket,
              const int* __restrict__ seg,
              const int* __restrict__ ovf_cnt,
              const int* __restrict__ ovf,
              float4* __restrict__ out4) {
    const int idx  = blockIdx.x * blockDim.x + threadIdx.x;   // [0, NSEG*64)
    const int lane = threadIdx.x & 63;
    const int s    = idx >> 6;
    if (s >= NSEG) return;
    gather_segment(s, lane & 15, lane >> 4, v4, cnt, bucket, seg, ovf_cnt, ovf, out4);
}

extern "C" void kernel_launch(void* const* d_in, const int* in_sizes, int n_in,
                              void* d_out, int out_size, void* d_ws, size_t ws_size,
                              hipStream_t stream) {
    const float4* v4  = (const float4*)d_in[1];
    const int*    seg = (const int*)d_in[2];

    int* cnt     = (int*)d_ws;
    int* ovf_cnt = cnt + NSEG;
    int* bucket  = ovf_cnt + 1;
    int* ovf     = bucket + NSEG * CAP;
    float4* out4 = (float4*)d_out;

    // Try the fused cooperative launch first.
    int maxb = 0;
    hipError_t e = hipOccupancyMaxActiveBlocksPerMultiprocessor(
        &maxb, (const void*)fused_kernel, NTHR, 0);
    if (e == hipSuccess && maxb > 0) {
        int nblk = maxb * 256;                  // 256 CUs on MI355X
        if (nblk > 2500) nblk = 2500;           // >= enough for wave-per-segment
        void* args[] = {(void*)&v4, (void*)&seg, (void*)&cnt, (void*)&ovf_cnt,
                        (void*)&bucket, (void*)&ovf, (void*)&out4};
        e = hipLaunchCooperativeKernel((void*)fused_kernel,
                                       dim3(nblk), dim3(NTHR), args, 0, stream);
        if (e == hipSuccess) return;
    }

    // Fallback: proven 3-dispatch path.
    hipMemsetAsync(cnt, 0, (size_t)(NSEG + 1) * sizeof(int), stream);
    bucket_kernel<<<(SS / 4 + NTHR - 1) / NTHR, NTHR, 0, stream>>>(
        (const int4*)seg, cnt, ovf_cnt, bucket, ovf);
    gather_kernel<<<(NSEG * 64 + NTHR - 1) / NTHR, NTHR, 0, stream>>>(
        v4, cnt, bucket, seg, ovf_cnt, ovf, out4);

    (void)in_sizes; (void)n_in; (void)out_size; (void)ws_size;
}

// Round 8
// 60.400 us; speedup vs baseline: 3.0320x; 3.0320x over previous
//
#include <hip/hip_runtime.h>

// Problem constants (match the JAX reference).
constexpr int NSEG = 10000;
constexpr int BB   = 4;
constexpr int SS   = 200000;    // divisible by 4
constexpr int DD   = 64;        // 16 float4 per row

constexpr int CAP     = 48;     // bucket capacity per segment (mean 20, P(>48) ~ 1e-8)
                                // CAP <= 64 so a wave holds a full bucket (1 int/lane)
constexpr int OVF_CAP = 4096;   // overflow list capacity (empty in practice)
constexpr int NTHR    = 256;

// ---------------------------------------------------------------------------
// Phase 1 (single pass): histogram + bucket scatter, int4-vectorized.
__global__ void bucket_kernel(const int4* __restrict__ seg4,
                              int* __restrict__ cnt,
                              int* __restrict__ ovf_cnt,
                              int* __restrict__ bucket,
                              int* __restrict__ ovf) {
    int i = blockIdx.x * blockDim.x + threadIdx.x;
    if (i >= SS / 4) return;
    int4 sg = seg4[i];
    int base = i * 4;
    int ss[4] = {sg.x, sg.y, sg.z, sg.w};
    #pragma unroll
    for (int k = 0; k < 4; ++k) {
        int s = ss[k];
        int p = atomicAdd(&cnt[s], 1);
        if (p < CAP) {
            bucket[s * CAP + p] = base + k;
        } else {
            int o = atomicAdd(ovf_cnt, 1);
            if (o < OVF_CAP) ovf[o] = base + k;
        }
    }
}

// ---------------------------------------------------------------------------
// Phase 2: gather-sum. One 64-lane wave per segment; lane = (d4, b).
// The wave's full index list lives in registers (1 int/lane, CAP<=64);
// rows are broadcast with __shfl so the inner loop issues ONLY the
// independent 16B v-loads (8 deep) — no index-load latency in the chain.
__global__ void __launch_bounds__(NTHR)
gather_kernel(const float4* __restrict__ v4,
              const int* __restrict__ cnt,
              const int* __restrict__ bucket,
              const int* __restrict__ seg,
              const int* __restrict__ ovf_cnt,
              const int* __restrict__ ovf,
              float4* __restrict__ out4) {
    const int idx  = blockIdx.x * blockDim.x + threadIdx.x;   // [0, NSEG*64)
    const int lane = threadIdx.x & 63;
    const int d4   = lane & 15;
    const int b    = lane >> 4;
    const int s    = idx >> 6;
    if (s >= NSEG) return;

    int n = cnt[s];
    if (n > CAP) n = CAP;

    // One coalesced 192B load per wave: lane L holds index of row L.
    const int myidx = (lane < n) ? bucket[s * CAP + lane] : 0;

    const float4* vb = v4 + (size_t)b * SS * 16;
    float4 acc = make_float4(0.f, 0.f, 0.f, 0.f);

    int j = 0;
    for (; j + 7 < n; j += 8) {                   // 8 independent loads in flight
        int r0 = __shfl(myidx, j + 0);
        int r1 = __shfl(myidx, j + 1);
        int r2 = __shfl(myidx, j + 2);
        int r3 = __shfl(myidx, j + 3);
        int r4 = __shfl(myidx, j + 4);
        int r5 = __shfl(myidx, j + 5);
        int r6 = __shfl(myidx, j + 6);
        int r7 = __shfl(myidx, j + 7);
        float4 a0 = vb[(size_t)r0 * 16 + d4];
        float4 a1 = vb[(size_t)r1 * 16 + d4];
        float4 a2 = vb[(size_t)r2 * 16 + d4];
        float4 a3 = vb[(size_t)r3 * 16 + d4];
        float4 a4 = vb[(size_t)r4 * 16 + d4];
        float4 a5 = vb[(size_t)r5 * 16 + d4];
        float4 a6 = vb[(size_t)r6 * 16 + d4];
        float4 a7 = vb[(size_t)r7 * 16 + d4];
        acc.x += ((a0.x + a1.x) + (a2.x + a3.x)) + ((a4.x + a5.x) + (a6.x + a7.x));
        acc.y += ((a0.y + a1.y) + (a2.y + a3.y)) + ((a4.y + a5.y) + (a6.y + a7.y));
        acc.z += ((a0.z + a1.z) + (a2.z + a3.z)) + ((a4.z + a5.z) + (a6.z + a7.z));
        acc.w += ((a0.w + a1.w) + (a2.w + a3.w)) + ((a4.w + a5.w) + (a6.w + a7.w));
    }
    for (; j + 3 < n; j += 4) {
        int r0 = __shfl(myidx, j + 0);
        int r1 = __shfl(myidx, j + 1);
        int r2 = __shfl(myidx, j + 2);
        int r3 = __shfl(myidx, j + 3);
        float4 a0 = vb[(size_t)r0 * 16 + d4];
        float4 a1 = vb[(size_t)r1 * 16 + d4];
        float4 a2 = vb[(size_t)r2 * 16 + d4];
        float4 a3 = vb[(size_t)r3 * 16 + d4];
        acc.x += (a0.x + a1.x) + (a2.x + a3.x);
        acc.y += (a0.y + a1.y) + (a2.y + a3.y);
        acc.z += (a0.z + a1.z) + (a2.z + a3.z);
        acc.w += (a0.w + a1.w) + (a2.w + a3.w);
    }
    for (; j < n; ++j) {
        int r0 = __shfl(myidx, j);
        float4 a0 = vb[(size_t)r0 * 16 + d4];
        acc.x += a0.x; acc.y += a0.y; acc.z += a0.z; acc.w += a0.w;
    }

    // Overflow fixup (rows beyond CAP) — empty in practice, one cached load.
    int no = *ovf_cnt;
    if (no > 0) {
        if (no > OVF_CAP) no = OVF_CAP;
        for (int t = 0; t < no; ++t) {
            int r = ovf[t];
            if (seg[r] == s) {
                float4 a0 = vb[(size_t)r * 16 + d4];
                acc.x += a0.x; acc.y += a0.y; acc.z += a0.z; acc.w += a0.w;
            }
        }
    }

    out4[((size_t)b * NSEG + s) * 16 + d4] = acc;     // written exactly once
}

// Fallback (round-1 kernel) in case ws_size is too small.
__global__ void scatter_atomic_kernel(const float4* __restrict__ v4,
                                      const int* __restrict__ seg,
                                      float* __restrict__ out) {
    const int total  = BB * SS * (DD / 4);
    const int stride = gridDim.x * blockDim.x;
    for (int idx = blockIdx.x * blockDim.x + threadIdx.x; idx < total; idx += stride) {
        const int d4 = idx & 15;
        const int t  = idx >> 4;
        const int i  = t % SS;
        const int b  = t / SS;
        const int sg = seg[i];
        const float4 val = v4[idx];
        float* o = out + ((size_t)b * NSEG + sg) * DD + d4 * 4;
        atomicAdd(o + 0, val.x);
        atomicAdd(o + 1, val.y);
        atomicAdd(o + 2, val.z);
        atomicAdd(o + 3, val.w);
    }
}

extern "C" void kernel_launch(void* const* d_in, const int* in_sizes, int n_in,
                              void* d_out, int out_size, void* d_ws, size_t ws_size,
                              hipStream_t stream) {
    const float4* v4  = (const float4*)d_in[1];
    const int*    seg = (const int*)d_in[2];

    // Workspace: cnt[NSEG] | ovf_cnt[1] | bucket[NSEG*CAP] | ovf[OVF_CAP]
    const size_t need = (size_t)(NSEG + 1 + NSEG * CAP + OVF_CAP) * sizeof(int);
    if (ws_size < need) {
        float* out = (float*)d_out;
        hipMemsetAsync(out, 0, (size_t)out_size * sizeof(float), stream);
        scatter_atomic_kernel<<<4096, 256, 0, stream>>>(v4, seg, out);
        return;
    }

    int* cnt     = (int*)d_ws;
    int* ovf_cnt = cnt + NSEG;
    int* bucket  = ovf_cnt + 1;
    int* ovf     = bucket + NSEG * CAP;

    // cnt + ovf_cnt must be zero every call (graph replays).
    hipMemsetAsync(cnt, 0, (size_t)(NSEG + 1) * sizeof(int), stream);

    bucket_kernel<<<(SS / 4 + NTHR - 1) / NTHR, NTHR, 0, stream>>>(
        (const int4*)seg, cnt, ovf_cnt, bucket, ovf);

    gather_kernel<<<(NSEG * 64 + NTHR - 1) / NTHR, NTHR, 0, stream>>>(
        v4, cnt, bucket, seg, ovf_cnt, ovf, (float4*)d_out);

    (void)in_sizes; (void)n_in; (void)out_size;
}